// Round 5
// baseline (251.165 us; speedup 1.0000x reference)
//
#include <hip/hip_runtime.h>
#include <stdint.h>

// Problem constants (match reference)
#define kN   20000
#define kE   160000
#define kET  (kN + kE)   // edges incl self loops = 180000
#define kF   256
#define kHID 64
#define kH   4
#define kHC  16
#define kC   10
#define kK   3
#define kCST 1e-5f
#define kBN  32          // nodes per proj block (625 blocks)

__device__ __forceinline__ uint16_t f2bf(float x) {
    uint32_t u = __float_as_uint(x);
    u += 0x7fffu + ((u >> 16) & 1u);   // round-to-nearest-even
    return (uint16_t)(u >> 16);
}
__device__ __forceinline__ float lo16(uint32_t p) { return __uint_as_float(p << 16); }
__device__ __forceinline__ float hi16(uint32_t p) { return __uint_as_float(p & 0xffff0000u); }
__device__ __forceinline__ uint32_t pack2(float a, float b) {
    return ((uint32_t)f2bf(b) << 16) | (uint32_t)f2bf(a);
}

// ---- degree histogram over col (incl self loops) ----
__global__ void deg_kernel(const int* __restrict__ ei, int* __restrict__ deg) {
    int e = blockIdx.x * blockDim.x + threadIdx.x;
    if (e >= kET) return;
    int c = (e < kE) ? ei[kE + e] : (e - kE);
    atomicAdd(&deg[c], 1);
}

// ---- single-block scan: deg -> ptr[0..N]; also computes gammas ----
__global__ __launch_bounds__(1024) void scan_kernel(
    const int* __restrict__ deg, int* __restrict__ ptr,
    const float* __restrict__ hopwise, const float* __restrict__ temp,
    float* __restrict__ gammas) {
    __shared__ int wsums[16];
    __shared__ int wexcl[16];
    const int CH = 20;               // 1024*20 = 20480 >= kN
    int t = threadIdx.x;
    int base = t * CH;
    int s = 0;
    for (int i = 0; i < CH; ++i) {
        int idx = base + i;
        if (idx < kN) s += deg[idx];
    }
    int incl = s;
#pragma unroll
    for (int off = 1; off < 64; off <<= 1) {
        int v = __shfl_up(incl, off, 64);
        if ((t & 63) >= off) incl += v;
    }
    int wid = t >> 6;
    if ((t & 63) == 63) wsums[wid] = incl;
    __syncthreads();
    if (t < 16) {
        int p = 0;
        for (int j = 0; j < t; ++j) p += wsums[j];
        wexcl[t] = p;
    }
    __syncthreads();
    int running = wexcl[wid] + incl - s;   // exclusive prefix at `base`
    for (int i = 0; i < CH; ++i) {
        int idx = base + i;
        if (idx < kN) { ptr[idx] = running; running += deg[idx]; }
    }
    if (base < kN && base + CH >= kN) ptr[kN] = running;
    if (t == 0) {
        for (int k = 1; k <= kK; ++k) {
            float mx = -1e30f;
            for (int h = 0; h < kH; ++h) mx = fmaxf(mx, temp[h * (kK + 1) + k]);
            float ex[kH]; float sum = 0.f;
            for (int h = 0; h < kH; ++h) { ex[h] = __expf(temp[h * (kK + 1) + k] - mx); sum += ex[h]; }
            for (int h = 0; h < kH; ++h) gammas[(k - 1) * kH + h] = hopwise[k] * ex[h] / sum;
        }
    }
}

// ---- CSR (by col) build: scatter (row, norm); norm from deg via rsqrt ----
__global__ void scatter_kernel(const int* __restrict__ ei, const int* __restrict__ deg,
                               const int* __restrict__ ptr, int* __restrict__ cursor,
                               int* __restrict__ src, float* __restrict__ wgt) {
    int e = blockIdx.x * blockDim.x + threadIdx.x;
    if (e >= kET) return;
    int r, c;
    if (e < kE) { r = ei[e]; c = ei[kE + e]; } else { r = c = e - kE; }
    float wv = rsqrtf((float)deg[r]) * rsqrtf((float)deg[c]);
    int pos = ptr[c] + atomicAdd(&cursor[c], 1);
    src[pos] = r;
    wgt[pos] = wv;
}

// ---- fused projections, 32 nodes/block x 625 blocks.
//      x = relu(feat@W_in+b); Q/K = 1+elu(x@Wq/Wk+b); V = x@Wv+b;
//      M0 = K outer V (bf16, canonical word p = values 2p,2p+1);
//      hidden = V*hopwise[0]; Q,Kt f32 to global.
__global__ __launch_bounds__(256) void proj_kernel(
    const float* __restrict__ feat, const float* __restrict__ W_in, const float* __restrict__ b_in,
    const float* __restrict__ Wq, const float* __restrict__ bq,
    const float* __restrict__ Wk, const float* __restrict__ bk,
    const float* __restrict__ Wv, const float* __restrict__ bv,
    const float* __restrict__ hopwise,
    float* __restrict__ Qg, float* __restrict__ Ktg, float* __restrict__ hidden,
    uint16_t* __restrict__ M) {
    __shared__ float sF[kBN * 68];   // feat k-tile, later Kt
    __shared__ float sW[64 * 68];    // W_in tile -> Wq -> Wk -> Wv
    __shared__ float sX[kBN * 68];   // x
    __shared__ float sV[kBN * 44];   // V

    int t = threadIdx.x;
    int tx = t & 15, ty = t >> 4;    // 16 x 16 thread grid
    int n0 = blockIdx.x * kBN;
    int r0 = ty * 2, r1 = ty * 2 + 1;

    // ---- phase 1: x = relu(feat @ W_in + b_in), K tiled by 64 ----
    float acc[2][4];
#pragma unroll
    for (int i = 0; i < 2; ++i)
#pragma unroll
        for (int j = 0; j < 4; ++j) acc[i][j] = 0.f;

    for (int ks = 0; ks < 4; ++ks) {
        int k0 = ks * 64;
#pragma unroll
        for (int i = 0; i < 2; ++i) {            // 32x16 float4 slots = 512
            int slot = t + 256 * i;
            int row = slot >> 4, cg = slot & 15;
            *(float4*)&sF[row * 68 + cg * 4] =
                *(const float4*)&feat[(size_t)(n0 + row) * kF + k0 + cg * 4];
        }
#pragma unroll
        for (int i = 0; i < 4; ++i) {            // 64x16 float4 slots = 1024
            int slot = t + 256 * i;
            int row = slot >> 4, cg = slot & 15;
            *(float4*)&sW[row * 68 + cg * 4] =
                *(const float4*)&W_in[(size_t)(k0 + row) * kHID + cg * 4];
        }
        __syncthreads();
#pragma unroll 8
        for (int kk = 0; kk < 64; ++kk) {
            float4 b = *(float4*)&sW[kk * 68 + tx * 4];
            float a0 = sF[r0 * 68 + kk], a1 = sF[r1 * 68 + kk];
            acc[0][0] += a0 * b.x; acc[0][1] += a0 * b.y;
            acc[0][2] += a0 * b.z; acc[0][3] += a0 * b.w;
            acc[1][0] += a1 * b.x; acc[1][1] += a1 * b.y;
            acc[1][2] += a1 * b.z; acc[1][3] += a1 * b.w;
        }
        __syncthreads();
    }
    {
        float bb[4];
#pragma unroll
        for (int j = 0; j < 4; ++j) bb[j] = b_in[tx * 4 + j];
#pragma unroll
        for (int i = 0; i < 2; ++i) {
            float4 xr;
            xr.x = fmaxf(acc[i][0] + bb[0], 0.f);
            xr.y = fmaxf(acc[i][1] + bb[1], 0.f);
            xr.z = fmaxf(acc[i][2] + bb[2], 0.f);
            xr.w = fmaxf(acc[i][3] + bb[3], 0.f);
            *(float4*)&sX[(r0 + i) * 68 + tx * 4] = xr;
        }
    }
    // stage Wq (sW free after last barrier above)
#pragma unroll
    for (int i = 0; i < 4; ++i) {
        int slot = t + 256 * i;
        int row = slot >> 4, cg = slot & 15;
        *(float4*)&sW[row * 68 + cg * 4] = *(const float4*)&Wq[(size_t)row * kHID + cg * 4];
    }
    __syncthreads();

    // ---- Q pass ----
    float qa[2][4];
#pragma unroll
    for (int i = 0; i < 2; ++i)
#pragma unroll
        for (int j = 0; j < 4; ++j) qa[i][j] = 0.f;
#pragma unroll 8
    for (int kk = 0; kk < 64; ++kk) {
        float4 b = *(float4*)&sW[kk * 68 + tx * 4];
        float a0 = sX[r0 * 68 + kk], a1 = sX[r1 * 68 + kk];
        qa[0][0] += a0 * b.x; qa[0][1] += a0 * b.y;
        qa[0][2] += a0 * b.z; qa[0][3] += a0 * b.w;
        qa[1][0] += a1 * b.x; qa[1][1] += a1 * b.y;
        qa[1][2] += a1 * b.z; qa[1][3] += a1 * b.w;
    }
    {
        float bqv[4];
#pragma unroll
        for (int j = 0; j < 4; ++j) bqv[j] = bq[tx * 4 + j];
#pragma unroll
        for (int i = 0; i < 2; ++i) {
            float4 qv;
            float q0 = qa[i][0] + bqv[0], q1 = qa[i][1] + bqv[1];
            float q2 = qa[i][2] + bqv[2], q3 = qa[i][3] + bqv[3];
            qv.x = (q0 > 0.f) ? 1.f + q0 : __expf(q0);
            qv.y = (q1 > 0.f) ? 1.f + q1 : __expf(q1);
            qv.z = (q2 > 0.f) ? 1.f + q2 : __expf(q2);
            qv.w = (q3 > 0.f) ? 1.f + q3 : __expf(q3);
            *(float4*)&Qg[(size_t)(n0 + r0 + i) * kHID + tx * 4] = qv;
        }
    }
    __syncthreads();
    // stage Wk
#pragma unroll
    for (int i = 0; i < 4; ++i) {
        int slot = t + 256 * i;
        int row = slot >> 4, cg = slot & 15;
        *(float4*)&sW[row * 68 + cg * 4] = *(const float4*)&Wk[(size_t)row * kHID + cg * 4];
    }
    __syncthreads();

    // ---- K pass ----
    float ka[2][4];
#pragma unroll
    for (int i = 0; i < 2; ++i)
#pragma unroll
        for (int j = 0; j < 4; ++j) ka[i][j] = 0.f;
#pragma unroll 8
    for (int kk = 0; kk < 64; ++kk) {
        float4 b = *(float4*)&sW[kk * 68 + tx * 4];
        float a0 = sX[r0 * 68 + kk], a1 = sX[r1 * 68 + kk];
        ka[0][0] += a0 * b.x; ka[0][1] += a0 * b.y;
        ka[0][2] += a0 * b.z; ka[0][3] += a0 * b.w;
        ka[1][0] += a1 * b.x; ka[1][1] += a1 * b.y;
        ka[1][2] += a1 * b.z; ka[1][3] += a1 * b.w;
    }
    {
        float bkv[4];
#pragma unroll
        for (int j = 0; j < 4; ++j) bkv[j] = bk[tx * 4 + j];
#pragma unroll
        for (int i = 0; i < 2; ++i) {
            float4 kv;
            float k0v = ka[i][0] + bkv[0], k1v = ka[i][1] + bkv[1];
            float k2v = ka[i][2] + bkv[2], k3v = ka[i][3] + bkv[3];
            kv.x = (k0v > 0.f) ? 1.f + k0v : __expf(k0v);
            kv.y = (k1v > 0.f) ? 1.f + k1v : __expf(k1v);
            kv.z = (k2v > 0.f) ? 1.f + k2v : __expf(k2v);
            kv.w = (k3v > 0.f) ? 1.f + k3v : __expf(k3v);
            *(float4*)&Ktg[(size_t)(n0 + r0 + i) * kHID + tx * 4] = kv;
            *(float4*)&sF[(r0 + i) * 68 + tx * 4] = kv;   // Kt into sF (feat tile dead)
        }
    }
    __syncthreads();
    // stage Wv as [64][44] (640 float4 slots)
#pragma unroll
    for (int i = 0; i < 3; ++i) {
        int slot = t + 256 * i;
        if (slot < 640) {
            int row = slot / 10, cg = slot % 10;
            *(float4*)&sW[row * 44 + cg * 4] = *(const float4*)&Wv[(size_t)row * 40 + cg * 4];
        }
    }
    __syncthreads();

    // ---- V pass (threads 0..159: 16 row-groups x 10 col-groups) ----
    if (t < 160) {
        int txv = t % 10, tyv = t / 10;
        int vr0 = tyv * 2;
        float va[2][4];
#pragma unroll
        for (int i = 0; i < 2; ++i)
#pragma unroll
            for (int j = 0; j < 4; ++j) va[i][j] = 0.f;
#pragma unroll 8
        for (int kk = 0; kk < 64; ++kk) {
            float4 b = *(float4*)&sW[kk * 44 + txv * 4];
            float a0 = sX[vr0 * 68 + kk], a1 = sX[(vr0 + 1) * 68 + kk];
            va[0][0] += a0 * b.x; va[0][1] += a0 * b.y;
            va[0][2] += a0 * b.z; va[0][3] += a0 * b.w;
            va[1][0] += a1 * b.x; va[1][1] += a1 * b.y;
            va[1][2] += a1 * b.z; va[1][3] += a1 * b.w;
        }
        float bvv[4];
#pragma unroll
        for (int j = 0; j < 4; ++j) bvv[j] = bv[txv * 4 + j];
        float hw0 = hopwise[0];
#pragma unroll
        for (int i = 0; i < 2; ++i) {
            int row = vr0 + i;
            float4 vr;
            vr.x = va[i][0] + bvv[0]; vr.y = va[i][1] + bvv[1];
            vr.z = va[i][2] + bvv[2]; vr.w = va[i][3] + bvv[3];
            *(float4*)&sV[row * 44 + txv * 4] = vr;
            float4 hr;
            hr.x = vr.x * hw0; hr.y = vr.y * hw0; hr.z = vr.z * hw0; hr.w = vr.w * hw0;
            *(float4*)&hidden[(size_t)(n0 + row) * 40 + txv * 4] = hr;
        }
    }
    __syncthreads();

    // ---- M phase: canonical word p holds values (2p, 2p+1); plane-coalesced stores.
    //      word p: h=p/80, i=(p%80)/5, j=p%5 -> Kt[h*16+i] * V[h*10+2j(+1)]
    int w = t >> 6, l = t & 63;
    uint32_t* Mw = (uint32_t*)M;
    int offK[5], offV[5];
#pragma unroll
    for (int c = 0; c < 5; ++c) {
        int p = l + 64 * c;
        int h = p / 80, r5 = p - h * 80;
        int i = r5 / 5, j = r5 - i * 5;
        offK[c] = h * 16 + i;
        offV[c] = h * 10 + 2 * j;
    }
#pragma unroll 2
    for (int it = 0; it < 8; ++it) {
        int node = it * 4 + w;
        uint32_t* dst = Mw + (size_t)(n0 + node) * 320 + l;
        const float* kb = &sF[node * 68];
        const float* vb = &sV[node * 44];
#pragma unroll
        for (int c = 0; c < 5; ++c) {
            float kt = kb[offK[c]];
            dst[64 * c] = pack2(kt * vb[offV[c]], kt * vb[offV[c] + 1]);
        }
    }
}

// ---- one hop, wave-per-node. Gather via 3 loads/edge/lane:
//      uint4 (words 4l..4l+3) + dword (word 256+l) + Kt f32.
//      8-deep edge unroll (24-load window spanning 8 edges).
//      LDS lane-major stride-12; epilogue remaps to canonical values.
//      LAST: skip M/Kt writeback, fuse output GEMM.
template<bool LAST>
__global__ __launch_bounds__(256, 4) void hop3_kernel(
    const int* __restrict__ ptr, const int* __restrict__ src, const float* __restrict__ wgt,
    const uint16_t* __restrict__ Min, uint16_t* __restrict__ Mout,
    const float* __restrict__ Ktin, float* __restrict__ Ktout,
    const float* __restrict__ Q, float* __restrict__ hidden,
    const float* __restrict__ gammas,
    const float* __restrict__ W_out, const float* __restrict__ b_out,
    float* __restrict__ out) {
    __shared__ float Ml[4][64 * 12];   // lane-major: [l*12+0..7]=words 4l..4l+3, [l*12+8..9]=word 256+l
    __shared__ float Ktl[4][64];
    __shared__ float Ql[4][64];
    __shared__ float Hl[4][40];
    int w = threadIdx.x >> 6;     // node slot
    int l = threadIdx.x & 63;     // lane
    int n = blockIdx.x * 4 + w;
    int beg = ptr[n], end = ptr[n + 1];
    const uint32_t* Mw = (const uint32_t*)Min;

    Ql[w][l] = Q[(size_t)n * 64 + l];   // hoisted: overlaps with gather

    float m0=0,m1=0,m2=0,m3=0,m4=0,m5=0,m6=0,m7=0,m8=0,m9=0;
    float kacc = 0.f;

    auto edge = [&](int su, float wvu) {
        const uint32_t* r = Mw + (size_t)su * 320;
        uint4 A = *(const uint4*)(r + 4 * l);
        uint32_t B = r[256 + l];
        float kv = Ktin[(size_t)su * 64 + l];
        m0 += wvu * lo16(A.x); m1 += wvu * hi16(A.x);
        m2 += wvu * lo16(A.y); m3 += wvu * hi16(A.y);
        m4 += wvu * lo16(A.z); m5 += wvu * hi16(A.z);
        m6 += wvu * lo16(A.w); m7 += wvu * hi16(A.w);
        m8 += wvu * lo16(B);   m9 += wvu * hi16(B);
        kacc += wvu * kv;
    };

    int e = beg;
    for (; e + 8 <= end; e += 8) {
        int s0 = src[e], s1 = src[e+1], s2 = src[e+2], s3 = src[e+3];
        int s4 = src[e+4], s5 = src[e+5], s6 = src[e+6], s7 = src[e+7];
        float w0 = wgt[e], w1 = wgt[e+1], w2 = wgt[e+2], w3 = wgt[e+3];
        float w4 = wgt[e+4], w5 = wgt[e+5], w6 = wgt[e+6], w7 = wgt[e+7];
        edge(s0, w0); edge(s1, w1); edge(s2, w2); edge(s3, w3);
        edge(s4, w4); edge(s5, w5); edge(s6, w6); edge(s7, w7);
    }
    if (e + 4 <= end) {
        int s0 = src[e], s1 = src[e+1], s2 = src[e+2], s3 = src[e+3];
        float w0 = wgt[e], w1 = wgt[e+1], w2 = wgt[e+2], w3 = wgt[e+3];
        edge(s0, w0); edge(s1, w1); edge(s2, w2); edge(s3, w3);
        e += 4;
    }
    if (e + 2 <= end) {
        int s0 = src[e], s1 = src[e+1];
        float w0 = wgt[e], w1 = wgt[e+1];
        edge(s0, w0); edge(s1, w1);
        e += 2;
    }
    if (e < end) edge(src[e], wgt[e]);

    // LDS staging: lane-major stride-12 (16B-aligned float4 stores)
    {
        float* dst = &Ml[w][l * 12];
        *(float4*)dst       = make_float4(m0, m1, m2, m3);
        *(float4*)(dst + 4) = make_float4(m4, m5, m6, m7);
        *(float2*)(dst + 8) = make_float2(m8, m9);
    }
    Ktl[w][l] = kacc;
    if constexpr (!LAST) {
        uint32_t* orow = (uint32_t*)Mout + (size_t)n * 320;
        uint4 o;
        o.x = pack2(m0, m1); o.y = pack2(m2, m3);
        o.z = pack2(m4, m5); o.w = pack2(m6, m7);
        *(uint4*)(orow + 4 * l) = o;
        orow[256 + l] = pack2(m8, m9);
        Ktout[(size_t)n * 64 + l] = kacc;
    }
    __syncthreads();

    int tt = threadIdx.x;
    if (tt < 160) {
        int ww = tt / 40, o = tt % 40;
        int h = o / 10, j = o % 10;
        const float* q  = &Ql[ww][h * 16];
        const float* kk = &Ktl[ww][h * 16];
        const float* mb = &Ml[ww][0];
        float cd = kCST, hh = 0.f;
#pragma unroll
        for (int i = 0; i < 16; ++i) {
            int v = h * 160 + i * 10 + j;       // canonical value index
            int wd = v >> 1, hf = v & 1;
            int addr = (wd < 256) ? ((wd >> 2) * 12 + 2 * (wd & 3) + hf)
                                  : ((wd - 256) * 12 + 8 + hf);
            cd += q[i] * kk[i];
            hh += q[i] * mb[addr];
        }
        int nn = blockIdx.x * 4 + ww;
        float val = hidden[(size_t)nn * 40 + o] + gammas[h] * hh / cd;
        if constexpr (!LAST) hidden[(size_t)nn * 40 + o] = val;
        else Hl[ww][o] = val;
    }
    if constexpr (LAST) {
        __syncthreads();
        if (tt < 40) {
            int ww = tt / 10, c = tt % 10;
            float acc = b_out[c];
#pragma unroll
            for (int i = 0; i < 40; ++i) acc += Hl[ww][i] * W_out[i * 10 + c];
            out[(size_t)(blockIdx.x * 4 + ww) * 10 + c] = acc;
        }
    }
}

extern "C" void kernel_launch(void* const* d_in, const int* in_sizes, int n_in,
                              void* d_out, int out_size, void* d_ws, size_t ws_size,
                              hipStream_t stream) {
    const float* feat   = (const float*)d_in[0];
    const int*   ei     = (const int*)d_in[1];
    const float* W_in   = (const float*)d_in[2];
    const float* b_in   = (const float*)d_in[3];
    const float* Wq     = (const float*)d_in[4];
    const float* bq     = (const float*)d_in[5];
    const float* Wk     = (const float*)d_in[6];
    const float* bk     = (const float*)d_in[7];
    const float* Wv     = (const float*)d_in[8];
    const float* bv     = (const float*)d_in[9];
    const float* W_out  = (const float*)d_in[10];
    const float* b_out  = (const float*)d_in[11];
    const float* hopwise= (const float*)d_in[12];
    const float* temp   = (const float*)d_in[13];
    float* out = (float*)d_out;

    char* ws = (char*)d_ws;
    size_t off = 0;
    auto alloc = [&](size_t bytes) -> void* {
        void* p = ws + off;
        off += (bytes + 255) & ~(size_t)255;
        return p;
    };
    int*      deg    = (int*)alloc((size_t)kN * 4);
    int*      cursor = (int*)alloc((size_t)kN * 4);
    int*      ptr    = (int*)alloc((size_t)(kN + 1) * 4);
    int*      csrc   = (int*)alloc((size_t)kET * 4);
    float*    cwgt   = (float*)alloc((size_t)kET * 4);
    float*    Q      = (float*)alloc((size_t)kN * kHID * 4);
    float*    Kt0    = (float*)alloc((size_t)kN * kHID * 4);
    float*    Kt1    = (float*)alloc((size_t)kN * kHID * 4);
    float*    hidden = (float*)alloc((size_t)kN * kH * kC * 4);
    float*    gammas = (float*)alloc(64);
    uint16_t* M0     = (uint16_t*)alloc((size_t)kN * 640 * 2);
    uint16_t* M1     = (uint16_t*)alloc((size_t)kN * 640 * 2);
    (void)ws_size; (void)in_sizes; (void)n_in; (void)out_size;

    // deg & cursor are adjacent in ws: one memset covers both
    size_t deg_span = (size_t)((char*)cursor - (char*)deg) + (size_t)kN * 4;
    hipMemsetAsync(deg, 0, deg_span, stream);

    deg_kernel<<<(kET + 255) / 256, 256, 0, stream>>>(ei, deg);
    scan_kernel<<<1, 1024, 0, stream>>>(deg, ptr, hopwise, temp, gammas);
    scatter_kernel<<<(kET + 255) / 256, 256, 0, stream>>>(ei, deg, ptr, cursor, csrc, cwgt);
    proj_kernel<<<kN / kBN, 256, 0, stream>>>(feat, W_in, b_in, Wq, bq, Wk, bk, Wv, bv,
                                              hopwise, Q, Kt0, hidden, M0);
    hop3_kernel<false><<<kN / 4, 256, 0, stream>>>(ptr, csrc, cwgt, M0, M1, Kt0, Kt1, Q, hidden,
                                                   gammas + 0, W_out, b_out, out);
    hop3_kernel<false><<<kN / 4, 256, 0, stream>>>(ptr, csrc, cwgt, M1, M0, Kt1, Kt0, Q, hidden,
                                                   gammas + 4, W_out, b_out, out);
    hop3_kernel<true><<<kN / 4, 256, 0, stream>>>(ptr, csrc, cwgt, M0, M1, Kt0, Kt1, Q, hidden,
                                                  gammas + 8, W_out, b_out, out);
}